// Round 8
// baseline (1211.905 us; speedup 1.0000x reference)
//
#include <hip/hip_runtime.h>
#include <math.h>

#define NN 12288
#define DD 128
#define EPSF 1e-7f
#define MAXNORM (1.0f - 1e-3f)
#define S_SLABS 12
#define JWIN 1024            // NN / S_SLABS
#define WROW 192             // 64-bit words per bitmask row (NN/64)

typedef __attribute__((ext_vector_type(8))) short short8_t;
typedef __attribute__((ext_vector_type(4))) float float4_t;
typedef unsigned short ushort_t;

__device__ __forceinline__ unsigned short f2bf(float f) {
    unsigned int u = __builtin_bit_cast(unsigned int, f);
    unsigned int r = u + 0x7FFFu + ((u >> 16) & 1u);
    return (unsigned short)(r >> 16);
}

// ---------------- Kernel 0: adj (int32) -> bitmask, fully coalesced ----------
// Each wave-iter: 256 consecutive ints (4 coalesced dword loads) -> 4 ballots
// -> one 32 B store by lane 0. Pure stream, fill-kernel-shaped.
__global__ __launch_bounds__(256) void compress_kernel(
    const int* __restrict__ adj, unsigned long long* __restrict__ bits)
{
    const int lane = threadIdx.x & 63;
    const int wid  = (blockIdx.x * 256 + threadIdx.x) >> 6;
    const int nw   = (gridDim.x * 256) >> 6;
    const size_t total = (size_t)NN * NN / 256;   // wave-iters
    for (size_t itr = wid; itr < total; itr += nw) {
        const size_t base = itr * 256;
        unsigned long long m0, m1, m2, m3;
        m0 = __ballot(adj[base +   0 + lane] > 0);
        m1 = __ballot(adj[base +  64 + lane] > 0);
        m2 = __ballot(adj[base + 128 + lane] > 0);
        m3 = __ballot(adj[base + 192 + lane] > 0);
        if (lane == 0) {
            ulonglong4 o; o.x = m0; o.y = m1; o.z = m2; o.w = m3;
            *(ulonglong4*)&bits[base >> 6] = o;
        }
    }
}

// ---------------- Kernel 1: per-row prep ----------------
__global__ __launch_bounds__(128) void prep_kernel(
    const float* __restrict__ x, const float* __restrict__ a,
    ushort_t* __restrict__ xtb,
    float* __restrict__ wh1, float* __restrict__ wh2)
{
    const int r = blockIdx.x;
    const int t = threadIdx.x;
    const float xv = x[r * DD + t];
    const float a1 = a[t];
    const float a2 = a[DD + t];
    float s0 = xv * xv, s1 = xv * a1, s2 = xv * a2;
    #pragma unroll
    for (int o = 32; o > 0; o >>= 1) {
        s0 += __shfl_xor(s0, o);
        s1 += __shfl_xor(s1, o);
        s2 += __shfl_xor(s2, o);
    }
    __shared__ float red[6];
    const int w = t >> 6;
    if ((t & 63) == 0) { red[w * 3 + 0] = s0; red[w * 3 + 1] = s1; red[w * 3 + 2] = s2; }
    __syncthreads();
    const float sumsq = red[0] + red[3];
    const float d1    = red[1] + red[4];
    const float d2    = red[2] + red[5];
    const float nraw  = sqrtf(sumsq);
    const float nrm   = fminf(fmaxf(nraw, EPSF), 1.0f - EPSF);
    const float scale = atanhf(nrm) / nrm;
    xtb[(size_t)r * DD + t] = f2bf(xv * scale);
    if (t == 0) {
        wh1[r] = scale * d1;
        wh2[r] = scale * d2;
    }
}

// ---------------- Kernel 2: build xtB in MFMA-B-fragment-linear layout ----
__global__ __launch_bounds__(256) void swizzle_kernel(
    const ushort_t* __restrict__ xtb, ushort_t* __restrict__ xtB)
{
    __shared__ ushort_t raw[32 * 136];
    const int C = blockIdx.x;
    const int t = threadIdx.x;
    #pragma unroll
    for (int p = 0; p < 2; ++p) {
        const int idx = p * 256 + t;
        const int j = idx >> 4, cell = idx & 15;
        const uint4 v = *(const uint4*)(xtb + (size_t)(C * 32 + j) * DD + cell * 8);
        *(uint4*)&raw[j * 136 + cell * 8] = v;
    }
    __syncthreads();
    #pragma unroll
    for (int p = 0; p < 2; ++p) {
        const int oc = p * 256 + t;       // 0..511 = dt*64 + lane
        const int dt = oc >> 6;
        const int l6 = oc & 63;
        const int l15 = l6 & 15, q = l6 >> 4;
        short8_t v;
        #pragma unroll
        for (int e = 0; e < 8; ++e)
            v[e] = (short)raw[(q * 8 + e) * 136 + dt * 16 + l15];
        *(short8_t*)(xtB + (size_t)C * 4096 + oc * 8) = v;
    }
}

// ---------------- Kernel 3: bitmask MFMA attention, B-frags reg-cached ------
// grid (48, 12). Block: 4 waves x 64 rows = 256 rows; j-slab 1024 in two
// 512-j windows (B restaged once). Per 128-j chunk: 32 B-frags + wh2 cached
// in registers, reused across 4 i-tiles. In-loop global traffic = bits only.
__global__ __launch_bounds__(256, 1) void attn_kernel(
    const unsigned int* __restrict__ bits,
    const ushort_t* __restrict__ xtB,
    const float* __restrict__ wh1, const float* __restrict__ wh2,
    float* __restrict__ pout, float* __restrict__ plsum)
{
    __shared__ __align__(16) ushort_t B_lds[512 * DD];   // 128 KB
    __shared__ __align__(16) float wh2_lds[512];         //   2 KB

    const int t = threadIdx.x;
    const int w = t >> 6, lane = t & 63;
    const int l15 = lane & 15, quad = lane >> 4;
    const int s = blockIdx.y;
    const int rowbase = blockIdx.x * 256 + w * 64;   // wave's 64 rows (4 i-tiles)

    float wh1r[4];
    #pragma unroll
    for (int it = 0; it < 4; ++it) wh1r[it] = wh1[rowbase + it * 16 + l15];

    float4_t acc[4][8];
    #pragma unroll
    for (int it = 0; it < 4; ++it)
        #pragma unroll
        for (int dt = 0; dt < 8; ++dt) acc[it][dt] = (float4_t)0.0f;
    float lsum[4] = {0.0f, 0.0f, 0.0f, 0.0f};

    for (int win = 0; win < 2; ++win) {
        const int jcol0 = s * JWIN + win * 512;
        if (win) __syncthreads();
        // ---- stage B (128 KB) + wh2 (2 KB) ----
        {
            const uint4* src = (const uint4*)(xtB + (size_t)(jcol0 >> 5) * 4096);
            uint4* dst = (uint4*)B_lds;
            #pragma unroll
            for (int m = 0; m < 32; ++m) dst[m * 256 + t] = src[m * 256 + t];
            wh2_lds[t]       = wh2[jcol0 + t];
            wh2_lds[256 + t] = wh2[jcol0 + 256 + t];
        }
        __syncthreads();

        #pragma unroll
        for (int jh = 0; jh < 4; ++jh) {
            // ---- bits for the 4 i-tiles (uint4 = 128 cols; quads broadcast) ----
            uint4 bw[4];
            #pragma unroll
            for (int it = 0; it < 4; ++it) {
                const int row = rowbase + it * 16 + l15;
                bw[it] = *(const uint4*)(bits + (size_t)row * (WROW * 2)
                                         + (jcol0 >> 5) + jh * 4);
            }
            // ---- cache B-frags + wh2 for this 128-j chunk in registers ----
            short8_t Bf[4][8];
            #pragma unroll
            for (int kc = 0; kc < 4; ++kc)
                #pragma unroll
                for (int dt = 0; dt < 8; ++dt)
                    Bf[kc][dt] = *(const short8_t*)
                        &B_lds[(jh * 4 + kc) * 4096 + dt * 512 + lane * 8];
            float4 Wa[4], Wb[4];
            #pragma unroll
            for (int kc = 0; kc < 4; ++kc) {
                const int wb = jh * 128 + kc * 32 + quad * 8;
                Wa[kc] = *(const float4*)&wh2_lds[wb];
                Wb[kc] = *(const float4*)&wh2_lds[wb + 4];
            }

            #pragma unroll
            for (int it = 0; it < 4; ++it) {
                const float wh1i = wh1r[it];
                const unsigned wk[4] = {bw[it].x, bw[it].y, bw[it].z, bw[it].w};
                #pragma unroll
                for (int kc = 0; kc < 4; ++kc) {
                    const unsigned byte = (wk[kc] >> (quad * 8)) & 0xffu;
                    const float u0 = wh1i + Wa[kc].x, u1 = wh1i + Wa[kc].y;
                    const float u2 = wh1i + Wa[kc].z, u3 = wh1i + Wa[kc].w;
                    const float u4 = wh1i + Wb[kc].x, u5 = wh1i + Wb[kc].y;
                    const float u6 = wh1i + Wb[kc].z, u7 = wh1i + Wb[kc].w;
                    const float p0 = (byte & 1u)   ? __expf(fmaxf(u0, 0.2f * u0)) : 0.0f;
                    const float p1 = (byte & 2u)   ? __expf(fmaxf(u1, 0.2f * u1)) : 0.0f;
                    const float p2 = (byte & 4u)   ? __expf(fmaxf(u2, 0.2f * u2)) : 0.0f;
                    const float p3 = (byte & 8u)   ? __expf(fmaxf(u3, 0.2f * u3)) : 0.0f;
                    const float p4 = (byte & 16u)  ? __expf(fmaxf(u4, 0.2f * u4)) : 0.0f;
                    const float p5 = (byte & 32u)  ? __expf(fmaxf(u5, 0.2f * u5)) : 0.0f;
                    const float p6 = (byte & 64u)  ? __expf(fmaxf(u6, 0.2f * u6)) : 0.0f;
                    const float p7 = (byte & 128u) ? __expf(fmaxf(u7, 0.2f * u7)) : 0.0f;
                    lsum[it] += ((p0 + p1) + (p2 + p3)) + ((p4 + p5) + (p6 + p7));
                    short8_t af;
                    af[0] = (short)f2bf(p0); af[1] = (short)f2bf(p1);
                    af[2] = (short)f2bf(p2); af[3] = (short)f2bf(p3);
                    af[4] = (short)f2bf(p4); af[5] = (short)f2bf(p5);
                    af[6] = (short)f2bf(p6); af[7] = (short)f2bf(p7);
                    #pragma unroll
                    for (int dt = 0; dt < 8; ++dt)
                        acc[it][dt] = __builtin_amdgcn_mfma_f32_16x16x32_bf16(
                            af, Bf[kc][dt], acc[it][dt], 0, 0, 0);
                }
            }
        }
    }

    // ---- epilogue ----
    #pragma unroll
    for (int it = 0; it < 4; ++it) {
        float v = lsum[it];
        v += __shfl_xor(v, 16);
        v += __shfl_xor(v, 32);
        const int row0 = rowbase + it * 16;
        if (quad == 0) plsum[(size_t)s * NN + row0 + l15] = v;
        #pragma unroll
        for (int dt = 0; dt < 8; ++dt)
            #pragma unroll
            for (int reg = 0; reg < 4; ++reg)
                pout[((size_t)s * NN + row0 + quad * 4 + reg) * DD + dt * 16 + l15]
                    = acc[it][dt][reg];
    }
}

// ---------------- Kernel 4: combine partials + normalize + expmap0 + proj ----
__global__ __launch_bounds__(128) void reduce_kernel(
    const float* __restrict__ pout, const float* __restrict__ plsum,
    float* __restrict__ out)
{
    const int i = blockIdx.x;
    const int t = threadIdx.x;
    float v = 0.0f;
    #pragma unroll
    for (int s = 0; s < S_SLABS; ++s) v += pout[((size_t)s * NN + i) * DD + t];
    float ls = 0.0f;
    #pragma unroll
    for (int s = 0; s < S_SLABS; ++s) ls += plsum[(size_t)s * NN + i];
    v /= ls;
    float ss = v * v;
    #pragma unroll
    for (int o = 1; o < 64; o <<= 1) ss += __shfl_xor(ss, o);
    __shared__ float r2[2];
    if ((t & 63) == 0) r2[t >> 6] = ss;
    __syncthreads();
    const float total = r2[0] + r2[1];
    const float nraw = sqrtf(total);
    const float nv   = fmaxf(nraw, EPSF);
    const float th   = tanhf(nv);
    const float ysc  = th / nv;
    const float nyr  = ysc * nraw;
    const float ny   = fmaxf(nyr, EPSF);
    const float psc  = (ny > MAXNORM) ? (MAXNORM / ny) : 1.0f;
    const float os   = ysc * psc;
    out[(size_t)i * DD + t] = v * os;
}

extern "C" void kernel_launch(void* const* d_in, const int* in_sizes, int n_in,
                              void* d_out, int out_size, void* d_ws, size_t ws_size,
                              hipStream_t stream) {
    const float* x   = (const float*)d_in[0];
    const int*   adj = (const int*)d_in[1];
    const float* a   = (const float*)d_in[2];
    float* out = (float*)d_out;

    // ---- workspace layout (~100 MB; ws is ~2.4 GB) ----
    char* ws = (char*)d_ws;
    unsigned long long* bits = (unsigned long long*)ws;
    ws += (size_t)NN * WROW * sizeof(unsigned long long);     // 18.9 MB
    ushort_t* xtb = (ushort_t*)ws;  ws += (size_t)NN * DD * sizeof(ushort_t);
    ushort_t* xtB = (ushort_t*)ws;  ws += (size_t)NN * DD * sizeof(ushort_t);
    float* wh1 = (float*)ws;        ws += NN * sizeof(float);
    float* wh2 = (float*)ws;        ws += NN * sizeof(float);
    float* plsum = (float*)ws;      ws += (size_t)S_SLABS * NN * sizeof(float);
    float* pout  = (float*)ws;

    compress_kernel<<<2048, 256, 0, stream>>>(adj, bits);
    prep_kernel<<<NN, 128, 0, stream>>>(x, a, xtb, wh1, wh2);
    swizzle_kernel<<<NN / 32, 256, 0, stream>>>(xtb, xtB);
    attn_kernel<<<dim3(NN / 256, S_SLABS), 256, 0, stream>>>(
        (const unsigned int*)bits, xtB, wh1, wh2, pout, plsum);
    reduce_kernel<<<NN, 128, 0, stream>>>(pout, plsum, out);
}

// Round 9
// 990.748 us; speedup vs baseline: 1.2232x; 1.2232x over previous
//
#include <hip/hip_runtime.h>
#include <math.h>

#define NN 12288
#define DD 128
#define EPSF 1e-7f
#define MAXNORM (1.0f - 1e-3f)
#define S_SLABS 12
#define JWIN 1024            // NN / S_SLABS, two 512-j windows per block
#define WROW 192             // 64-bit words per bitmask row (NN/64)

typedef __attribute__((ext_vector_type(8))) short short8_t;
typedef __attribute__((ext_vector_type(4))) float float4_t;
typedef unsigned short ushort_t;

__device__ __forceinline__ unsigned short f2bf(float f) {
    unsigned int u = __builtin_bit_cast(unsigned int, f);
    unsigned int r = u + 0x7FFFu + ((u >> 16) & 1u);
    return (unsigned short)(r >> 16);
}

// ---------------- Kernel 0: adj (int32) -> bitmask, fully coalesced ----------
__global__ __launch_bounds__(256) void compress_kernel(
    const int* __restrict__ adj, unsigned long long* __restrict__ bits)
{
    const int lane = threadIdx.x & 63;
    const int wid  = (blockIdx.x * 256 + threadIdx.x) >> 6;
    const int nw   = (gridDim.x * 256) >> 6;
    const size_t total = (size_t)NN * NN / 256;   // wave-iters
    for (size_t itr = wid; itr < total; itr += nw) {
        const size_t base = itr * 256;
        unsigned long long m0, m1, m2, m3;
        m0 = __ballot(adj[base +   0 + lane] > 0);
        m1 = __ballot(adj[base +  64 + lane] > 0);
        m2 = __ballot(adj[base + 128 + lane] > 0);
        m3 = __ballot(adj[base + 192 + lane] > 0);
        if (lane == 0) {
            ulonglong4 o; o.x = m0; o.y = m1; o.z = m2; o.w = m3;
            *(ulonglong4*)&bits[base >> 6] = o;
        }
    }
}

// ---------------- Kernel 1: per-row prep ----------------
__global__ __launch_bounds__(128) void prep_kernel(
    const float* __restrict__ x, const float* __restrict__ a,
    ushort_t* __restrict__ xtb,
    float* __restrict__ wh1, float* __restrict__ wh2)
{
    const int r = blockIdx.x;
    const int t = threadIdx.x;
    const float xv = x[r * DD + t];
    const float a1 = a[t];
    const float a2 = a[DD + t];
    float s0 = xv * xv, s1 = xv * a1, s2 = xv * a2;
    #pragma unroll
    for (int o = 32; o > 0; o >>= 1) {
        s0 += __shfl_xor(s0, o);
        s1 += __shfl_xor(s1, o);
        s2 += __shfl_xor(s2, o);
    }
    __shared__ float red[6];
    const int w = t >> 6;
    if ((t & 63) == 0) { red[w * 3 + 0] = s0; red[w * 3 + 1] = s1; red[w * 3 + 2] = s2; }
    __syncthreads();
    const float sumsq = red[0] + red[3];
    const float d1    = red[1] + red[4];
    const float d2    = red[2] + red[5];
    const float nraw  = sqrtf(sumsq);
    const float nrm   = fminf(fmaxf(nraw, EPSF), 1.0f - EPSF);
    const float scale = atanhf(nrm) / nrm;
    xtb[(size_t)r * DD + t] = f2bf(xv * scale);
    if (t == 0) {
        wh1[r] = scale * d1;
        wh2[r] = scale * d2;
    }
}

// ---------------- Kernel 2: build xtB in MFMA-fragment-linear layout ----
// chunk C (32 j), dt: cell (lane, e) = xt[C*32+(lane>>4)*8+e][dt*16+(lane&15)].
// Serves as the A-operand layout (m=lane&15 -> d, k=quad*8+e -> j).
__global__ __launch_bounds__(256) void swizzle_kernel(
    const ushort_t* __restrict__ xtb, ushort_t* __restrict__ xtB)
{
    __shared__ ushort_t raw[32 * 136];
    const int C = blockIdx.x;
    const int t = threadIdx.x;
    #pragma unroll
    for (int p = 0; p < 2; ++p) {
        const int idx = p * 256 + t;
        const int j = idx >> 4, cell = idx & 15;
        const uint4 v = *(const uint4*)(xtb + (size_t)(C * 32 + j) * DD + cell * 8);
        *(uint4*)&raw[j * 136 + cell * 8] = v;
    }
    __syncthreads();
    #pragma unroll
    for (int p = 0; p < 2; ++p) {
        const int oc = p * 256 + t;       // 0..511 = dt*64 + lane
        const int dt = oc >> 6;
        const int l6 = oc & 63;
        const int l15 = l6 & 15, q = l6 >> 4;
        short8_t v;
        #pragma unroll
        for (int e = 0; e < 8; ++e)
            v[e] = (short)raw[(q * 8 + e) * 136 + dt * 16 + l15];
        *(short8_t*)(xtB + (size_t)C * 4096 + oc * 8) = v;
    }
}

// ---------------- Kernel 3: operand-swapped MFMA attention -----------------
// grid (48, 12). Block: 4 waves x 64 rows = 256 rows x 1024-j slab (two 512-j
// windows, acc persists). A = xt (LDS, reused across 4 i-tiles as transient),
// B = p (registers). acc[4][8] = C[d][i] tiles. Zero in-loop VMEM: bits are
// preloaded per window ahead of the B-stage in the vmcnt queue.
__global__ __launch_bounds__(256, 1) void attn_kernel(
    const unsigned int* __restrict__ bits,
    const ushort_t* __restrict__ xtB,
    const float* __restrict__ wh1, const float* __restrict__ wh2,
    float* __restrict__ pout, float* __restrict__ plsum)
{
    __shared__ __align__(16) ushort_t B_lds[512 * DD];   // 128 KB
    __shared__ __align__(16) float wh2_lds[512];         //   2 KB

    const int t = threadIdx.x;
    const int w = t >> 6, lane = t & 63;
    const int l15 = lane & 15, quad = lane >> 4;
    const int s = blockIdx.y;
    const int rowbase = blockIdx.x * 256 + w * 64;   // wave's 64 rows (4 i-tiles)

    float wh1r[4];
    #pragma unroll
    for (int it = 0; it < 4; ++it) wh1r[it] = wh1[rowbase + it * 16 + l15];

    float4_t acc[4][8];
    #pragma unroll
    for (int it = 0; it < 4; ++it)
        #pragma unroll
        for (int dt = 0; dt < 8; ++dt) acc[it][dt] = (float4_t)0.0f;
    float lsum[4] = {0.0f, 0.0f, 0.0f, 0.0f};

    for (int win = 0; win < 2; ++win) {
        const int jcol0 = s * JWIN + win * 512;
        if (win) __syncthreads();            // all reads of previous window done

        // ---- bits for this window: issued FIRST in the vmcnt queue ----
        unsigned bm[4][16];
        #pragma unroll
        for (int it = 0; it < 4; ++it) {
            const unsigned int* bp = bits + (size_t)(rowbase + it * 16 + l15) * (WROW * 2)
                                     + (jcol0 >> 5);
            #pragma unroll
            for (int jh = 0; jh < 4; ++jh) {
                const uint4 v = *(const uint4*)(bp + jh * 4);
                bm[it][jh * 4 + 0] = v.x; bm[it][jh * 4 + 1] = v.y;
                bm[it][jh * 4 + 2] = v.z; bm[it][jh * 4 + 3] = v.w;
            }
        }

        // ---- stage B (128 KB) + wh2 (2 KB) ----
        {
            const uint4* src = (const uint4*)(xtB + (size_t)(jcol0 >> 5) * 4096);
            uint4* dst = (uint4*)B_lds;
            #pragma unroll
            for (int m = 0; m < 32; ++m) dst[m * 256 + t] = src[m * 256 + t];
            wh2_lds[t]       = wh2[jcol0 + t];
            wh2_lds[256 + t] = wh2[jcol0 + 256 + t];
        }
        __syncthreads();

        #pragma unroll
        for (int jh = 0; jh < 4; ++jh) {
            #pragma unroll
            for (int kc = 0; kc < 4; ++kc) {
                // A-frags (xt) for this 32-j chunk — shared by all 4 i-tiles
                short8_t Af[8];
                #pragma unroll
                for (int dt = 0; dt < 8; ++dt)
                    Af[dt] = *(const short8_t*)
                        &B_lds[(jh * 4 + kc) * 4096 + dt * 512 + lane * 8];
                const int wb = jh * 128 + kc * 32 + quad * 8;
                const float4 Wa = *(const float4*)&wh2_lds[wb];
                const float4 Wc = *(const float4*)&wh2_lds[wb + 4];

                #pragma unroll
                for (int it = 0; it < 4; ++it) {
                    const unsigned byte = (bm[it][jh * 4 + kc] >> (quad * 8)) & 0xffu;
                    const float wh1i = wh1r[it];
                    const float u0 = wh1i + Wa.x, u1 = wh1i + Wa.y;
                    const float u2 = wh1i + Wa.z, u3 = wh1i + Wa.w;
                    const float u4 = wh1i + Wc.x, u5 = wh1i + Wc.y;
                    const float u6 = wh1i + Wc.z, u7 = wh1i + Wc.w;
                    const float p0 = (byte & 1u)   ? __expf(fmaxf(u0, 0.2f * u0)) : 0.0f;
                    const float p1 = (byte & 2u)   ? __expf(fmaxf(u1, 0.2f * u1)) : 0.0f;
                    const float p2 = (byte & 4u)   ? __expf(fmaxf(u2, 0.2f * u2)) : 0.0f;
                    const float p3 = (byte & 8u)   ? __expf(fmaxf(u3, 0.2f * u3)) : 0.0f;
                    const float p4 = (byte & 16u)  ? __expf(fmaxf(u4, 0.2f * u4)) : 0.0f;
                    const float p5 = (byte & 32u)  ? __expf(fmaxf(u5, 0.2f * u5)) : 0.0f;
                    const float p6 = (byte & 64u)  ? __expf(fmaxf(u6, 0.2f * u6)) : 0.0f;
                    const float p7 = (byte & 128u) ? __expf(fmaxf(u7, 0.2f * u7)) : 0.0f;
                    lsum[it] += ((p0 + p1) + (p2 + p3)) + ((p4 + p5) + (p6 + p7));
                    short8_t pf;
                    pf[0] = (short)f2bf(p0); pf[1] = (short)f2bf(p1);
                    pf[2] = (short)f2bf(p2); pf[3] = (short)f2bf(p3);
                    pf[4] = (short)f2bf(p4); pf[5] = (short)f2bf(p5);
                    pf[6] = (short)f2bf(p6); pf[7] = (short)f2bf(p7);
                    #pragma unroll
                    for (int dt = 0; dt < 8; ++dt)
                        acc[it][dt] = __builtin_amdgcn_mfma_f32_16x16x32_bf16(
                            Af[dt], pf, acc[it][dt], 0, 0, 0);   // C[d][i]
                }
            }
        }
    }

    // ---- epilogue: C[d][i] -> pout[i][d] ----
    #pragma unroll
    for (int it = 0; it < 4; ++it) {
        float v = lsum[it];
        v += __shfl_xor(v, 16);
        v += __shfl_xor(v, 32);
        const int row0 = rowbase + it * 16;
        if (quad == 0) plsum[(size_t)s * NN + row0 + l15] = v;
        // lane (l15, quad), reg: i = row0 + l15, d = dt*16 + quad*4 + reg
        #pragma unroll
        for (int dt = 0; dt < 8; ++dt)
            *(float4_t*)&pout[((size_t)s * NN + row0 + l15) * DD + dt * 16 + quad * 4]
                = acc[it][dt];
    }
}

// ---------------- Kernel 4: combine partials + normalize + expmap0 + proj ----
__global__ __launch_bounds__(128) void reduce_kernel(
    const float* __restrict__ pout, const float* __restrict__ plsum,
    float* __restrict__ out)
{
    const int i = blockIdx.x;
    const int t = threadIdx.x;
    float v = 0.0f;
    #pragma unroll
    for (int s = 0; s < S_SLABS; ++s) v += pout[((size_t)s * NN + i) * DD + t];
    float ls = 0.0f;
    #pragma unroll
    for (int s = 0; s < S_SLABS; ++s) ls += plsum[(size_t)s * NN + i];
    v /= ls;
    float ss = v * v;
    #pragma unroll
    for (int o = 1; o < 64; o <<= 1) ss += __shfl_xor(ss, o);
    __shared__ float r2[2];
    if ((t & 63) == 0) r2[t >> 6] = ss;
    __syncthreads();
    const float total = r2[0] + r2[1];
    const float nraw = sqrtf(total);
    const float nv   = fmaxf(nraw, EPSF);
    const float th   = tanhf(nv);
    const float ysc  = th / nv;
    const float nyr  = ysc * nraw;
    const float ny   = fmaxf(nyr, EPSF);
    const float psc  = (ny > MAXNORM) ? (MAXNORM / ny) : 1.0f;
    const float os   = ysc * psc;
    out[(size_t)i * DD + t] = v * os;
}

extern "C" void kernel_launch(void* const* d_in, const int* in_sizes, int n_in,
                              void* d_out, int out_size, void* d_ws, size_t ws_size,
                              hipStream_t stream) {
    const float* x   = (const float*)d_in[0];
    const int*   adj = (const int*)d_in[1];
    const float* a   = (const float*)d_in[2];
    float* out = (float*)d_out;

    // ---- workspace layout (~101 MB; ws is ~2.4 GB) ----
    char* ws = (char*)d_ws;
    unsigned long long* bits = (unsigned long long*)ws;
    ws += (size_t)NN * WROW * sizeof(unsigned long long);     // 18.9 MB
    ushort_t* xtb = (ushort_t*)ws;  ws += (size_t)NN * DD * sizeof(ushort_t);
    ushort_t* xtB = (ushort_t*)ws;  ws += (size_t)NN * DD * sizeof(ushort_t);
    float* wh1 = (float*)ws;        ws += NN * sizeof(float);
    float* wh2 = (float*)ws;        ws += NN * sizeof(float);
    float* plsum = (float*)ws;      ws += (size_t)S_SLABS * NN * sizeof(float);
    float* pout  = (float*)ws;

    compress_kernel<<<2048, 256, 0, stream>>>(adj, bits);
    prep_kernel<<<NN, 128, 0, stream>>>(x, a, xtb, wh1, wh2);
    swizzle_kernel<<<NN / 32, 256, 0, stream>>>(xtb, xtB);
    attn_kernel<<<dim3(NN / 256, S_SLABS), 256, 0, stream>>>(
        (const unsigned int*)bits, xtB, wh1, wh2, pout, plsum);
    reduce_kernel<<<NN, 128, 0, stream>>>(pout, plsum, out);
}